// Round 1
// baseline (24033.739 us; speedup 1.0000x reference)
//
#include <hip/hip_runtime.h>
#include <hip/hip_bf16.h>

// LSTM_19902878449909: persistent fused recurrent kernel for MI355X.
// Structure: pack kernels (weights->MFMA-frag bf16, x->[t][b][k] bf16, zero h/bar)
// then one persistent kernel: 256 WGs (1/CU), producer waves (x@Wi, 1 step ahead)
// + consumer waves (h@Wh + gates + c), grid sync via device-scope atomic counter,
// h broadcast via agent-scope (L3-coherent) atomic b64 loads/stores.

typedef __attribute__((ext_vector_type(8))) short short8;     // 8 bf16 = 4 VGPRs (MFMA A/B frag)
typedef __attribute__((ext_vector_type(4))) float floatx4;    // MFMA C/D frag
typedef __attribute__((ext_vector_type(4))) unsigned int uint4v;
typedef unsigned long long u64;
typedef unsigned short u16;

#define NB 128
#define NTT 1024

// Device-global scratch (BSS) -- avoids any dependence on ws_size.
__device__ __attribute__((aligned(256))) u16 g_xpack[(size_t)NTT * NB * 1024]; // [t][b][k] bf16, 256 MB
__device__ __attribute__((aligned(256))) u16 g_wpack[2][4194304];              // [mat(i/h)][cb][ks][nt][lane*8], 8 MB each
__device__ __attribute__((aligned(256))) u16 g_hbuf[2][NB * 1024];             // h ping-pong, bf16
__device__ __attribute__((aligned(256))) unsigned g_bar;                       // monotonic barrier counter

__device__ __forceinline__ u16 f2bf(float f) {   // fp32 -> bf16 RNE
  unsigned u = __float_as_uint(f);
  u += 0x7FFFu + ((u >> 16) & 1u);
  return (u16)(u >> 16);
}

// ---- pack weights into B-fragment order ------------------------------------
// B-frag (mfma_f32_16x16x32_bf16): lane l holds B[k = ks*32 + (l>>4)*8 + j][n = l&15].
// Column list per cb (64 gate cols): nt0=[i|f]@hc0, nt1=[g|o]@hc0, nt2=[i|f]@hc1, nt3=[g|o]@hc1
// with hc(wn) = cb*16 + wn*8; n<8 -> first seg, n>=8 -> second seg.
__global__ void pack_w(const float* __restrict__ Wii, const float* __restrict__ Wif,
                       const float* __restrict__ Wig, const float* __restrict__ Wio,
                       const float* __restrict__ Whi, const float* __restrict__ Whf,
                       const float* __restrict__ Whg, const float* __restrict__ Who) {
  int wid = (blockIdx.x << 2) | (threadIdx.x >> 6);  // 0..16383
  int lane = threadIdx.x & 63;
  int mat = wid >> 13;          // 0 = Wi, 1 = Wh
  int rem = wid & 8191;
  int cb = rem >> 7;
  int ks = (rem >> 2) & 31;
  int nt = rem & 3;
  int n = lane & 15, quad = lane >> 4;
  const float *Wlo, *Whi2;
  if (mat == 0) { Wlo = (nt & 1) ? Wig : Wii; Whi2 = (nt & 1) ? Wio : Wif; }
  else          { Wlo = (nt & 1) ? Whg : Whi; Whi2 = (nt & 1) ? Who : Whf; }
  const float* src = (n < 8) ? Wlo : Whi2;
  int col = (cb << 4) + ((nt >> 1) << 3) + (n & 7);
  int k0 = (ks << 5) + (quad << 3);
  u16 tmp[8];
#pragma unroll
  for (int j = 0; j < 8; ++j) tmp[j] = f2bf(src[(size_t)(k0 + j) * 1024 + col]);
  *(uint4v*)&g_wpack[mat][((size_t)((cb * 32 + ks) * 4 + nt) << 9) + lane * 8] = *(uint4v*)tmp;
}

// ---- pack x: [b][t][k] fp32 -> [t][b][k] bf16; also zero g_hbuf / g_bar ----
__global__ void pack_x(const float* __restrict__ x) {
  int pair = threadIdx.x >> 7;            // 2 (b,t) pairs per 256-thread block
  int kt = (threadIdx.x & 127) << 3;      // 8 elements per thread
  int bt = (blockIdx.x << 1) | pair;      // 0..131071
  int b = bt >> 10, t = bt & 1023;
  const float* src = x + ((size_t)b * 1024 + t) * 1024 + kt;
  u16 tmp[8];
#pragma unroll
  for (int j = 0; j < 8; ++j) tmp[j] = f2bf(src[j]);
  *(uint4v*)&g_xpack[((size_t)t * NB + b) * 1024 + kt] = *(uint4v*)tmp;
  if (bt < 256) {  // zero both h buffers (2*131072 u16 = 256 blocks * 1024)
    size_t base = ((size_t)bt << 10) + ((size_t)(threadIdx.x & 127) << 3);
    uint4v z = {0u, 0u, 0u, 0u};
    *(uint4v*)&((u16*)g_hbuf)[base] = z;
  }
  if (bt == 0 && threadIdx.x == 0) g_bar = 0u;
}

// ---- main persistent kernel ------------------------------------------------
__global__ __launch_bounds__(256, 1) void lstm_main(
    const float* __restrict__ bi, const float* __restrict__ bf,
    const float* __restrict__ bg, const float* __restrict__ bo,
    float* __restrict__ out) {
  __shared__ u16 whlds[65536];         // Wh slice for this cb, frag order: 128 KB
  __shared__ float xbuf[2][32][68];    // x-projection handoff (fp32, +4 pad), 17 KB

  const int tid = threadIdx.x;
  const int wave = tid >> 6, lane = tid & 63;
  const int wm = wave >> 1, wn = wave & 1;   // wm=0: producer, wm=1: consumer
  const int wg = blockIdx.x;
  const int xcd = wg & 7;                    // blocks round-robin over 8 XCDs
  const int rb = xcd & 3;                    // one row-block per XCD (h L2 reuse)
  const int cb = ((xcd >> 2) << 5) | (wg >> 3);  // contiguous 512-col range per XCD
  const int rowbase = rb << 5;
  const int n = lane & 15, quad = lane >> 4;

  { // fill Wh LDS once (one-time cost, layout == packed global layout)
    const u16* src = &g_wpack[1][(size_t)cb << 16];
#pragma unroll 4
    for (int i = 0; i < 32; ++i) {
      int off = ((i << 8) + tid) << 3;
      *(uint4v*)&whlds[off] = *(const uint4v*)&src[off];
    }
  }

  const int colb = (cb << 4) | (wn << 3) | (n & 7);
  const float bias0 = (n < 8) ? bi[colb] : bf[colb];   // nt even = [i|f]
  const float bias1 = (n < 8) ? bg[colb] : bo[colb];   // nt odd  = [g|o]

  float creg[2][4];   // consumer-resident cell state: rows (m*16+quad*4+r), col (n&7)
#pragma unroll
  for (int m = 0; m < 2; ++m)
#pragma unroll
    for (int r = 0; r < 4; ++r) creg[m][r] = 0.f;

  const u16* wip = &g_wpack[0][(size_t)cb << 16];

  __syncthreads();

  for (int tt = 0; tt <= 1024; ++tt) {
    __syncthreads();
    // arrive for h(tt-2): all waves' stores of iter tt-1 retired before this syncthreads
    if (tid == 128 && tt >= 2)
      __hip_atomic_fetch_add(&g_bar, 1u, __ATOMIC_RELAXED, __HIP_MEMORY_SCOPE_AGENT);

    if (wm == 0) {
      if (tt < 1024) {
        // -------- producer: xpart(tt) = bias + x_tt @ Wi, into xbuf[tt&1] ----
        const u16* xp = &g_xpack[((size_t)tt * NB + rowbase) << 10];
        floatx4 acc[2][2];
#pragma unroll
        for (int m = 0; m < 2; ++m) {
          acc[m][0] = floatx4{bias0, bias0, bias0, bias0};
          acc[m][1] = floatx4{bias1, bias1, bias1, bias1};
        }
        short8 A[2][2][8], Bf2[2][2][8];   // double-buffered 8-kstep chunks
#pragma unroll
        for (int k8 = 0; k8 < 8; ++k8) {
#pragma unroll
          for (int m = 0; m < 2; ++m)
            A[0][m][k8] = *(const short8*)&xp[(((m << 4) | n) << 10) + (k8 << 5) + (quad << 3)];
#pragma unroll
          for (int q = 0; q < 2; ++q)
            Bf2[0][q][k8] = *(const short8*)&wip[(((k8 << 2) | (wn << 1) | q) << 9) + (lane << 3)];
        }
#pragma unroll
        for (int c = 0; c < 4; ++c) {
          if (c < 3) {
#pragma unroll
            for (int k8 = 0; k8 < 8; ++k8) {
              int ks = ((c + 1) << 3) | k8;
#pragma unroll
              for (int m = 0; m < 2; ++m)
                A[(c + 1) & 1][m][k8] =
                    *(const short8*)&xp[(((m << 4) | n) << 10) + (ks << 5) + (quad << 3)];
#pragma unroll
              for (int q = 0; q < 2; ++q)
                Bf2[(c + 1) & 1][q][k8] =
                    *(const short8*)&wip[(((ks << 2) | (wn << 1) | q) << 9) + (lane << 3)];
            }
          }
#pragma unroll
          for (int k8 = 0; k8 < 8; ++k8)
#pragma unroll
            for (int m = 0; m < 2; ++m)
#pragma unroll
              for (int q = 0; q < 2; ++q)
                acc[m][q] = __builtin_amdgcn_mfma_f32_16x16x32_bf16(
                    A[c & 1][m][k8], Bf2[c & 1][q][k8], acc[m][q], 0, 0, 0);
        }
        int p = tt & 1;
#pragma unroll
        for (int m = 0; m < 2; ++m)
#pragma unroll
          for (int q = 0; q < 2; ++q)
#pragma unroll
            for (int r = 0; r < 4; ++r)
              xbuf[p][(m << 4) + (quad << 2) + r][(((wn << 1) | q) << 4) | n] = acc[m][q][r];
      }
    } else if (tt >= 1) {
      // -------- consumer: step t = tt-1 --------------------------------------
      const int t = tt - 1;
      const unsigned target = (unsigned)t << 8;   // 256 arrivals per completed step
      if (target) {
        int guard = 0;
        for (;;) {
          unsigned cur = 0;
          if (lane == 0)
            cur = __hip_atomic_load(&g_bar, __ATOMIC_RELAXED, __HIP_MEMORY_SCOPE_AGENT);
          cur = __builtin_amdgcn_readfirstlane(cur);
          if (cur >= target) break;
          __builtin_amdgcn_s_sleep(4);
          if (++guard > 65536) break;   // safety valve: deadlock -> wrong-answer, not hang
        }
      }
      floatx4 acc[2][2];
      int p = t & 1;
#pragma unroll
      for (int m = 0; m < 2; ++m)
#pragma unroll
        for (int q = 0; q < 2; ++q)
#pragma unroll
          for (int r = 0; r < 4; ++r)
            acc[m][q][r] = xbuf[p][(m << 4) + (quad << 2) + r][(((wn << 1) | q) << 4) | n];

      // h(t-1) A-frags: agent-scope (L3-coherent) b64 loads; 16-kstep chunks, dbuf
      const u16* hp = &g_hbuf[(t + 1) & 1][rowbase << 10];
      u64 A2[2][2][16][2];
#pragma unroll
      for (int kk = 0; kk < 16; ++kk)
#pragma unroll
        for (int m = 0; m < 2; ++m) {
          const u64* ap = (const u64*)&hp[(((m << 4) | n) << 10) + (kk << 5) + (quad << 3)];
          A2[0][m][kk][0] = __hip_atomic_load(ap, __ATOMIC_RELAXED, __HIP_MEMORY_SCOPE_AGENT);
          A2[0][m][kk][1] = __hip_atomic_load(ap + 1, __ATOMIC_RELAXED, __HIP_MEMORY_SCOPE_AGENT);
        }
#pragma unroll
      for (int c = 0; c < 2; ++c) {
        if (c == 0) {
#pragma unroll
          for (int kk = 0; kk < 16; ++kk)
#pragma unroll
            for (int m = 0; m < 2; ++m) {
              const u64* ap =
                  (const u64*)&hp[(((m << 4) | n) << 10) + ((16 + kk) << 5) + (quad << 3)];
              A2[1][m][kk][0] = __hip_atomic_load(ap, __ATOMIC_RELAXED, __HIP_MEMORY_SCOPE_AGENT);
              A2[1][m][kk][1] = __hip_atomic_load(ap + 1, __ATOMIC_RELAXED, __HIP_MEMORY_SCOPE_AGENT);
            }
        }
#pragma unroll
        for (int kk = 0; kk < 16; ++kk) {
          int ks = (c << 4) | kk;
          short8 b0 = *(const short8*)&whlds[(((ks << 2) | (wn << 1)) << 9) + (lane << 3)];
          short8 b1 = *(const short8*)&whlds[(((ks << 2) | (wn << 1) | 1) << 9) + (lane << 3)];
#pragma unroll
          for (int m = 0; m < 2; ++m) {
            union { u64 u[2]; short8 s; } av;
            av.u[0] = A2[c][m][kk][0];
            av.u[1] = A2[c][m][kk][1];
            acc[m][0] = __builtin_amdgcn_mfma_f32_16x16x32_bf16(av.s, b0, acc[m][0], 0, 0, 0);
            acc[m][1] = __builtin_amdgcn_mfma_f32_16x16x32_bf16(av.s, b1, acc[m][1], 0, 0, 0);
          }
        }
      }
      // -------- epilogue: gates, c update, h store ---------------------------
      // C/D layout: col = lane&15, row = quad*4 + r. tile0 = [i|f], tile1 = [g|o].
      const int colbase = (cb << 4) | (wn << 3);
      u16* hw = &g_hbuf[t & 1][0];
#pragma unroll
      for (int m = 0; m < 2; ++m)
#pragma unroll
        for (int r = 0; r < 4; ++r) {
          float v0 = acc[m][0][r], v1 = acc[m][1][r];
          float q0 = __shfl_xor(v0, 8, 64);
          float q1 = __shfl_xor(v1, 8, 64);
          bool lo = (n < 8);
          float ipre = lo ? v0 : q0;
          float fpre = lo ? q0 : v0;
          float gpre = lo ? v1 : q1;
          float opre = lo ? q1 : v1;
          float iv = 1.f / (1.f + __expf(-ipre));
          float fv = 1.f / (1.f + __expf(-fpre));
          float eg = __expf(2.f * gpre);
          float gv = 1.f - 2.f / (eg + 1.f);       // tanh
          float ov = 1.f / (1.f + __expf(-opre));
          float cn = fv * creg[m][r] + iv * gv;
          creg[m][r] = cn;
          float ec = __expf(2.f * cn);
          float tc = 1.f - 2.f / (ec + 1.f);       // tanh(c)
          float hn = ov * tc;
          int row = rowbase + (m << 4) + (quad << 2) + r;
          if (t < 1023) {
            unsigned hv = (unsigned)f2bf(hn);
            unsigned u01 = (hv & 0xFFFFu) | (((unsigned)__shfl_xor((int)hv, 1, 64)) << 16);
            unsigned u23 = (unsigned)__shfl_xor((int)u01, 2, 64);
            if (lo && (n & 3) == 0) {   // lanes n in {0,4}: one 8B store of 4 bf16
              u64 pk = (u64)u01 | ((u64)u23 << 32);
              __hip_atomic_store((u64*)&hw[(row << 10) + colbase + n], pk,
                                 __ATOMIC_RELAXED, __HIP_MEMORY_SCOPE_AGENT);
            }
          } else if (lo) {              // final step: fp32 h and c to d_out
            int col = colbase | n;
            out[(row << 10) + col] = hn;
            out[131072 + (row << 10) + col] = cn;
          }
        }
      __builtin_amdgcn_s_waitcnt(0);   // h stores visible at L3 before next arrive
    }
  }
}

extern "C" void kernel_launch(void* const* d_in, const int* in_sizes, int n_in,
                              void* d_out, int out_size, void* d_ws, size_t ws_size,
                              hipStream_t stream) {
  const float* x   = (const float*)d_in[0];
  const float* Wii = (const float*)d_in[1];
  const float* Wif = (const float*)d_in[2];
  const float* Wig = (const float*)d_in[3];
  const float* Wio = (const float*)d_in[4];
  const float* Whi = (const float*)d_in[5];
  const float* Whf = (const float*)d_in[6];
  const float* Whg = (const float*)d_in[7];
  const float* Who = (const float*)d_in[8];
  const float* bi  = (const float*)d_in[9];
  const float* bf_ = (const float*)d_in[10];
  const float* bg  = (const float*)d_in[11];
  const float* bo  = (const float*)d_in[12];
  float* out = (float*)d_out;

  pack_w<<<4096, 256, 0, stream>>>(Wii, Wif, Wig, Wio, Whi, Whf, Whg, Who);
  pack_x<<<65536, 256, 0, stream>>>(x);
  lstm_main<<<256, 256, 0, stream>>>(bi, bf_, bg, bo, out);
}

// Round 2
// 19835.921 us; speedup vs baseline: 1.2116x; 1.2116x over previous
//
#include <hip/hip_runtime.h>
#include <hip/hip_bf16.h>

// LSTM_19902878449909: persistent fused recurrent kernel for MI355X. R2.
// Changes vs R1: (1) write-once rotating h buffers -> consumers use plain
// cached loads (no agent-scope atomic-load serialization, L2 shares lines
// across the 32 same-rb WGs per XCD); (2) per-rb arrival counters + single
// global poller per WG with LDS epoch broadcast (kills single-line barrier
// hammering); (3) register-sane load pipelines (4-kstep producer dbuf,
// 8-kstep consumer dbuf) to stop AGPR spill shuffling.

typedef __attribute__((ext_vector_type(8))) short short8;     // 8 bf16 = 4 VGPRs (MFMA A/B frag)
typedef __attribute__((ext_vector_type(4))) float floatx4;    // MFMA C/D frag
typedef __attribute__((ext_vector_type(4))) unsigned int uint4v;
typedef unsigned long long u64;
typedef unsigned short u16;

#define NB 128
#define NTT 1024

// Device-global scratch (BSS) -- avoids any dependence on ws_size.
__device__ __attribute__((aligned(256))) u16 g_xpack[(size_t)NTT * NB * 1024]; // [t][b][k] bf16, 256 MB
__device__ __attribute__((aligned(256))) u16 g_wpack[2][4194304];              // [mat(i/h)][cb][ks][nt][lane*8], 8 MB each
__device__ __attribute__((aligned(256))) u16 g_hall[NTT][NB * 1024];           // write-once h per step, 256 MB
__device__ __attribute__((aligned(256))) unsigned g_cnt[4 * 64];               // per-rb arrival counters, 256B apart

__device__ __forceinline__ u16 f2bf(float f) {   // fp32 -> bf16 RNE
  unsigned u = __float_as_uint(f);
  u += 0x7FFFu + ((u >> 16) & 1u);
  return (u16)(u >> 16);
}

// ---- pack weights into B-fragment order ------------------------------------
// B-frag (mfma_f32_16x16x32_bf16): lane l holds B[k = ks*32 + (l>>4)*8 + j][n = l&15].
// Column list per cb (64 gate cols): nt0=[i|f]@hc0, nt1=[g|o]@hc0, nt2=[i|f]@hc1, nt3=[g|o]@hc1
// with hc(wn) = cb*16 + wn*8; n<8 -> first seg, n>=8 -> second seg.
__global__ void pack_w(const float* __restrict__ Wii, const float* __restrict__ Wif,
                       const float* __restrict__ Wig, const float* __restrict__ Wio,
                       const float* __restrict__ Whi, const float* __restrict__ Whf,
                       const float* __restrict__ Whg, const float* __restrict__ Who) {
  int wid = (blockIdx.x << 2) | (threadIdx.x >> 6);  // 0..16383
  int lane = threadIdx.x & 63;
  int mat = wid >> 13;          // 0 = Wi, 1 = Wh
  int rem = wid & 8191;
  int cb = rem >> 7;
  int ks = (rem >> 2) & 31;
  int nt = rem & 3;
  int n = lane & 15, quad = lane >> 4;
  const float *Wlo, *Whi2;
  if (mat == 0) { Wlo = (nt & 1) ? Wig : Wii; Whi2 = (nt & 1) ? Wio : Wif; }
  else          { Wlo = (nt & 1) ? Whg : Whi; Whi2 = (nt & 1) ? Who : Whf; }
  const float* src = (n < 8) ? Wlo : Whi2;
  int col = (cb << 4) + ((nt >> 1) << 3) + (n & 7);
  int k0 = (ks << 5) + (quad << 3);
  u16 tmp[8];
#pragma unroll
  for (int j = 0; j < 8; ++j) tmp[j] = f2bf(src[(size_t)(k0 + j) * 1024 + col]);
  *(uint4v*)&g_wpack[mat][((size_t)((cb * 32 + ks) * 4 + nt) << 9) + lane * 8] = *(uint4v*)tmp;
}

// ---- pack x: [b][t][k] fp32 -> [t][b][k] bf16; zero g_hall[0] / counters ----
__global__ void pack_x(const float* __restrict__ x) {
  int pair = threadIdx.x >> 7;            // 2 (b,t) pairs per 256-thread block
  int kt = (threadIdx.x & 127) << 3;      // 8 elements per thread
  int bt = (blockIdx.x << 1) | pair;      // 0..131071
  int b = bt >> 10, t = bt & 1023;
  const float* src = x + ((size_t)b * 1024 + t) * 1024 + kt;
  u16 tmp[8];
#pragma unroll
  for (int j = 0; j < 8; ++j) tmp[j] = f2bf(src[j]);
  *(uint4v*)&g_xpack[((size_t)t * NB + b) * 1024 + kt] = *(uint4v*)tmp;
  if (bt < 128) {  // zero g_hall[0]: 131072 u16 = 128 * 128 threads * 8
    size_t base = ((size_t)bt << 10) + ((size_t)(threadIdx.x & 127) << 3);
    uint4v z = {0u, 0u, 0u, 0u};
    *(uint4v*)&g_hall[0][base] = z;
  }
  if (bt == 0 && threadIdx.x == 0) {
#pragma unroll
    for (int r = 0; r < 4; ++r) g_cnt[r << 6] = 0u;
  }
}

// ---- main persistent kernel ------------------------------------------------
__global__ __launch_bounds__(256, 1) void lstm_main(
    const float* __restrict__ bi, const float* __restrict__ bf,
    const float* __restrict__ bg, const float* __restrict__ bo,
    float* __restrict__ out) {
  __shared__ u16 whlds[65536];         // Wh slice for this cb, frag order: 128 KB
  __shared__ float xbuf[2][32][68];    // x-projection handoff (fp32, +4 pad), 17 KB
  __shared__ unsigned ld_epoch;        // step-complete epoch, wave2 -> wave3

  const int tid = threadIdx.x;
  const int wave = tid >> 6, lane = tid & 63;
  const int wm = wave >> 1, wn = wave & 1;   // wm=0: producer, wm=1: consumer
  const int wg = blockIdx.x;
  const int xcd = wg & 7;                    // blocks round-robin over 8 XCDs
  const int rb = xcd & 3;                    // one row-block per XCD (h L2 reuse)
  const int cb = ((xcd >> 2) << 5) | (wg >> 3);  // contiguous 512-col range per XCD
  const int rowbase = rb << 5;
  const int n = lane & 15, quad = lane >> 4;

  if (tid == 0) ld_epoch = 0u;

  { // fill Wh LDS once (one-time cost, layout == packed global layout)
    const u16* src = &g_wpack[1][(size_t)cb << 16];
#pragma unroll 4
    for (int i = 0; i < 32; ++i) {
      int off = ((i << 8) + tid) << 3;
      *(uint4v*)&whlds[off] = *(const uint4v*)&src[off];
    }
  }

  const int colb = (cb << 4) | (wn << 3) | (n & 7);
  const float bias0 = (n < 8) ? bi[colb] : bf[colb];   // nt even = [i|f]
  const float bias1 = (n < 8) ? bg[colb] : bo[colb];   // nt odd  = [g|o]

  float creg[2][4];   // consumer-resident cell state: rows (m*16+quad*4+r), col (n&7)
#pragma unroll
  for (int m = 0; m < 2; ++m)
#pragma unroll
    for (int r = 0; r < 4; ++r) creg[m][r] = 0.f;

  const u16* wip = &g_wpack[0][(size_t)cb << 16];
  unsigned* cnt = &g_cnt[rb << 6];

  __syncthreads();

  for (int tt = 0; tt <= 1024; ++tt) {
    __syncthreads();
    // arrive: my WG finished iter tt-1 (h(tt-2) stores drained pre-barrier)
    if (tid == 128 && tt >= 2)
      __hip_atomic_fetch_add(cnt, 1u, __ATOMIC_RELAXED, __HIP_MEMORY_SCOPE_AGENT);

    if (wm == 0) {
      if (tt < 1024) {
        // -------- producer: xpart(tt) = bias + x_tt @ Wi, into xbuf[tt&1] ----
        const u16* xp = &g_xpack[((size_t)tt * NB + rowbase) << 10];
        floatx4 acc[2][2];
#pragma unroll
        for (int m = 0; m < 2; ++m) {
          acc[m][0] = floatx4{bias0, bias0, bias0, bias0};
          acc[m][1] = floatx4{bias1, bias1, bias1, bias1};
        }
        short8 A[2][2][4], Bv[2][2][4];   // 4-kstep chunks, double-buffered
#pragma unroll
        for (int j = 0; j < 4; ++j) {
#pragma unroll
          for (int m = 0; m < 2; ++m)
            A[0][m][j] = *(const short8*)&xp[(((m << 4) | n) << 10) + (j << 5) + (quad << 3)];
#pragma unroll
          for (int q = 0; q < 2; ++q)
            Bv[0][q][j] = *(const short8*)&wip[(((j << 2) | (wn << 1) | q) << 9) + (lane << 3)];
        }
#pragma unroll
        for (int c = 0; c < 8; ++c) {
          int cur = c & 1, nxt = cur ^ 1;
          if (c < 7) {
#pragma unroll
            for (int j = 0; j < 4; ++j) {
              int ks = ((c + 1) << 2) | j;
#pragma unroll
              for (int m = 0; m < 2; ++m)
                A[nxt][m][j] =
                    *(const short8*)&xp[(((m << 4) | n) << 10) + (ks << 5) + (quad << 3)];
#pragma unroll
              for (int q = 0; q < 2; ++q)
                Bv[nxt][q][j] =
                    *(const short8*)&wip[(((ks << 2) | (wn << 1) | q) << 9) + (lane << 3)];
            }
          }
#pragma unroll
          for (int j = 0; j < 4; ++j)
#pragma unroll
            for (int m = 0; m < 2; ++m)
#pragma unroll
              for (int q = 0; q < 2; ++q)
                acc[m][q] = __builtin_amdgcn_mfma_f32_16x16x32_bf16(
                    A[cur][m][j], Bv[cur][q][j], acc[m][q], 0, 0, 0);
        }
        int p = tt & 1;
#pragma unroll
        for (int m = 0; m < 2; ++m)
#pragma unroll
          for (int q = 0; q < 2; ++q)
#pragma unroll
            for (int r = 0; r < 4; ++r)
              xbuf[p][(m << 4) + (quad << 2) + r][(((wn << 1) | q) << 4) | n] = acc[m][q][r];
      }
    } else if (tt >= 1) {
      // -------- consumer: step t = tt-1 --------------------------------------
      const int t = tt - 1;
      if (t > 0) {
        const unsigned target = (unsigned)t << 6;   // 64 arrivals per rb-group step
        if (wave == 2) {
          int guard = 0;
          for (;;) {
            unsigned cur = 0;
            if (lane == 0)
              cur = __hip_atomic_load(cnt, __ATOMIC_RELAXED, __HIP_MEMORY_SCOPE_AGENT);
            cur = __builtin_amdgcn_readfirstlane(cur);
            if (cur >= target) break;
            __builtin_amdgcn_s_sleep(2);
            if (++guard > (1 << 20)) break;   // deadlock -> wrong answer, not hang
          }
          if (lane == 0) *(volatile unsigned*)&ld_epoch = (unsigned)t;
        } else {
          int guard = 0;
          while (*(volatile unsigned*)&ld_epoch < (unsigned)t) {
            __builtin_amdgcn_s_sleep(2);
            if (++guard > (1 << 20)) break;
          }
        }
      }
      asm volatile("" ::: "memory");   // no load hoisting above the wait

      floatx4 acc[2][2];
      int p = t & 1;
#pragma unroll
      for (int m = 0; m < 2; ++m)
#pragma unroll
        for (int q = 0; q < 2; ++q)
#pragma unroll
          for (int r = 0; r < 4; ++r)
            acc[m][q][r] = xbuf[p][(m << 4) + (quad << 2) + r][(((wn << 1) | q) << 4) | n];

      // h(t-1) A-frags: plain cached loads from write-once buffer g_hall[t]
      const u16* hp = &g_hall[t][rowbase << 10];
      short8 A[2][2][8];   // 8-kstep chunks, double-buffered
#pragma unroll
      for (int j = 0; j < 8; ++j)
#pragma unroll
        for (int m = 0; m < 2; ++m)
          A[0][m][j] = *(const short8*)&hp[(((m << 4) | n) << 10) + (j << 5) + (quad << 3)];
#pragma unroll
      for (int c = 0; c < 4; ++c) {
        int cur = c & 1, nxt = cur ^ 1;
        if (c < 3) {
#pragma unroll
          for (int j = 0; j < 8; ++j) {
            int ks = ((c + 1) << 3) | j;
#pragma unroll
            for (int m = 0; m < 2; ++m)
              A[nxt][m][j] =
                  *(const short8*)&hp[(((m << 4) | n) << 10) + (ks << 5) + (quad << 3)];
          }
        }
#pragma unroll
        for (int j = 0; j < 8; ++j) {
          int ks = (c << 3) | j;
          short8 b0 = *(const short8*)&whlds[(((ks << 2) | (wn << 1)) << 9) + (lane << 3)];
          short8 b1 = *(const short8*)&whlds[(((ks << 2) | (wn << 1) | 1) << 9) + (lane << 3)];
#pragma unroll
          for (int m = 0; m < 2; ++m) {
            acc[m][0] = __builtin_amdgcn_mfma_f32_16x16x32_bf16(A[cur][m][j], b0, acc[m][0], 0, 0, 0);
            acc[m][1] = __builtin_amdgcn_mfma_f32_16x16x32_bf16(A[cur][m][j], b1, acc[m][1], 0, 0, 0);
          }
        }
      }
      // -------- epilogue: gates, c update, h store ---------------------------
      // C/D layout: col = lane&15, row = quad*4 + r. tile0 = [i|f], tile1 = [g|o].
      const int colbase = (cb << 4) | (wn << 3);
      u16* hw = (t < 1023) ? &g_hall[t + 1][0] : (u16*)0;
#pragma unroll
      for (int m = 0; m < 2; ++m)
#pragma unroll
        for (int r = 0; r < 4; ++r) {
          float v0 = acc[m][0][r], v1 = acc[m][1][r];
          float q0 = __shfl_xor(v0, 8, 64);
          float q1 = __shfl_xor(v1, 8, 64);
          bool lo = (n < 8);
          float ipre = lo ? v0 : q0;
          float fpre = lo ? q0 : v0;
          float gpre = lo ? v1 : q1;
          float opre = lo ? q1 : v1;
          float iv = 1.f / (1.f + __expf(-ipre));
          float fv = 1.f / (1.f + __expf(-fpre));
          float eg = __expf(2.f * gpre);
          float gv = 1.f - 2.f / (eg + 1.f);       // tanh
          float ov = 1.f / (1.f + __expf(-opre));
          float cn = fv * creg[m][r] + iv * gv;
          creg[m][r] = cn;
          float ec = __expf(2.f * cn);
          float tc = 1.f - 2.f / (ec + 1.f);       // tanh(c)
          float hn = ov * tc;
          int row = rowbase + (m << 4) + (quad << 2) + r;
          if (t < 1023) {
            unsigned hv = (unsigned)f2bf(hn);
            unsigned u01 = (hv & 0xFFFFu) | (((unsigned)__shfl_xor((int)hv, 1, 64)) << 16);
            unsigned u23 = (unsigned)__shfl_xor((int)u01, 2, 64);
            if (lo && (n & 3) == 0) {   // lanes n in {0,4}: one 8B store of 4 bf16
              u64 pk = (u64)u01 | ((u64)u23 << 32);
              __hip_atomic_store((u64*)&hw[(row << 10) + colbase + n], pk,
                                 __ATOMIC_RELAXED, __HIP_MEMORY_SCOPE_AGENT);
            }
          } else if (lo) {              // final step: fp32 h and c to d_out
            int col = colbase | n;
            out[(row << 10) + col] = hn;
            out[131072 + (row << 10) + col] = cn;
          }
        }
      asm volatile("" ::: "memory");
      __builtin_amdgcn_s_waitcnt(0);   // h stores visible at MALL before next arrive
    }
  }
}

extern "C" void kernel_launch(void* const* d_in, const int* in_sizes, int n_in,
                              void* d_out, int out_size, void* d_ws, size_t ws_size,
                              hipStream_t stream) {
  const float* x   = (const float*)d_in[0];
  const float* Wii = (const float*)d_in[1];
  const float* Wif = (const float*)d_in[2];
  const float* Wig = (const float*)d_in[3];
  const float* Wio = (const float*)d_in[4];
  const float* Whi = (const float*)d_in[5];
  const float* Whf = (const float*)d_in[6];
  const float* Whg = (const float*)d_in[7];
  const float* Who = (const float*)d_in[8];
  const float* bi  = (const float*)d_in[9];
  const float* bf_ = (const float*)d_in[10];
  const float* bg  = (const float*)d_in[11];
  const float* bo  = (const float*)d_in[12];
  float* out = (float*)d_out;

  pack_w<<<4096, 256, 0, stream>>>(Wii, Wif, Wig, Wio, Whi, Whf, Whg, Who);
  pack_x<<<65536, 256, 0, stream>>>(x);
  lstm_main<<<256, 256, 0, stream>>>(bi, bf_, bg, bo, out);
}